// Round 5
// baseline (101.154 us; speedup 1.0000x reference)
//
#include <hip/hip_runtime.h>

// RenderingModel: scatter-add of 64x64 filters at N particle positions onto a
// 512x512 canvas (cropped). Gather formulation: each block owns a 32x32 output
// tile AND a 1024-particle segment (grid.z = 8). Phase 1 compacts hits into
// LDS; phase 2 accumulates in registers; epilogue combines segments with
// global fp32 atomicAdd (d_out zeroed via hipMemsetAsync).
//
// Ledger on the ~38us render kernel (bench window = ~41us harness ws-poison
// fill + render + small node overheads):
//   R5  -45% phase-2 VALU (padded filters)      -> NEUTRAL
//   R6  removed ALL 2M global atomics (planes)  -> NEUTRAL (reduce node ~ -1us
//       vs memset, planes traffic +9MB; R4 atomic path remains best measured)
//   R7  single-node cooperative                 -> REGRESSION (grid.sync +23us)
//       but gave render counters: occ 95%, VALU-busy ~15us, FETCH 22MB, VGPR 20
//   R8  2-deep explicit load pipeline, bounds(256,4) -> NEUTRAL/NEG (extra VALU
//       + grid needed 2 residency rounds)
// => render is bound by the VECTOR-MEMORY REQUEST STREAM (TA issue + L1 line
// thrash + per-CU L2 bandwidth; each term 8-19us and they stack), not VALU,
// not atomics, not latency.
//
// R8 -> R9: attack the request stream itself. Per hit, validity of each of
// the 4 acc-rows (y = ybase + 8q) depends only on wave-uniform values (row is
// SGPR via readfirstlane; a wave spans y rows {ybw, ybw+1}) -> a SCALAR
// branch (s_cbranch, no divergence) skips the {med3, addr, load, select, add}
// of rows no lane needs: ~32% of phase-2 load instructions and their L1/L2
// line traffic, ~25% of phase-2 VALU. Skipped rows contributed exactly 0 ->
// bitwise-identical output (R7 passed with this exact body). Structure
// reverted to the best-measured R4 shape: memset + atomic render, 2 nodes,
// __launch_bounds__(256,8) = 2048-block grid exactly co-resident in 1 round.

#define H_  512
#define W_  512
#define FH_ 64
#define FW_ 64
#define TILE_ 32
#define THREADS_ 256
#define SEG_LEN_ 1024   // particles per segment; LDS list sized to this

__device__ __forceinline__ int clamp63(int v) {
    return min(max(v, 0), 63);   // -> v_med3_i32
}

__global__ __launch_bounds__(THREADS_, 8)
void render_tile_kernel(const int* __restrict__ phw,
                        const float* __restrict__ filters,
                        float* __restrict__ out, int n) {
    __shared__ unsigned int s_list[SEG_LEN_];
    __shared__ int s_cnt;

    const int t   = threadIdx.x;
    const int tx0 = blockIdx.x * TILE_;
    const int ty0 = blockIdx.y * TILE_;
    const int k0  = blockIdx.z * SEG_LEN_;
    const int k1  = (k0 + SEG_LEN_ < n) ? (k0 + SEG_LEN_) : n;

    if (t == 0) s_cnt = 0;
    __syncthreads();

    // ---- Phase 1: bbox test + compaction of this segment into LDS ----
    for (int k = k0 + t; k < k1; k += THREADS_) {
        const int part = phw[k * 3 + 0];
        const int row  = phw[k * 3 + 1];
        const int col  = phw[k * 3 + 2];
        const bool hit =
            (row >= ty0 - (FH_ / 2 - 1)) && (row <= ty0 + TILE_ - 1 + FH_ / 2) &&
            (col >= tx0 - (FW_ / 2 - 1)) && (col <= tx0 + TILE_ - 1 + FW_ / 2);
        if (hit) {
            const int idx = atomicAdd(&s_cnt, 1);
            // pack: part(8b) | row(9b) | col(9b)
            s_list[idx] = ((unsigned)part << 18) | ((unsigned)row << 9) | (unsigned)col;
        }
    }
    __syncthreads();
    const int cnt = s_cnt;

    // ---- Phase 2: accumulate owned pixels in registers ----
    // Thread t owns pixels (x = tx0 + (t&31), y = ty0 + (t>>5) + 8q), q=0..3.
    const int xl    = t & 31;
    const int yb    = t >> 5;          // 0..7
    const int x     = tx0 + xl;
    const int ybase = ty0 + yb;
    // Wave-uniform row base: lanes of one wave have yb in {ybw, ybw+1}.
    const int ybw   = (int)__builtin_amdgcn_readfirstlane(yb);

    float acc0 = 0.f, acc1 = 0.f, acc2 = 0.f, acc3 = 0.f;

    // One hit's contribution. Entries are wave-uniform -> readfirstlane puts
    // part/row/col in SGPRs; loads are SGPR-base + small vector offset.
    // Per-row validity is wave-uniform (A is scalar): rows no lane needs are
    // skipped by a SCALAR branch -> their load never issues (cuts ~32% of
    // phase-2 vector-memory requests). Surviving rows use the proven
    // branchless clamped-address + value-select form.
    auto body = [&](unsigned v) {
        const int part = (int)__builtin_amdgcn_readfirstlane(v >> 18);
        const int row  = (int)__builtin_amdgcn_readfirstlane((v >> 9) & 511u);
        const int col  = (int)__builtin_amdgcn_readfirstlane(v & 511u);
        const float* __restrict__ f = filters + (part << 12);  // SGPR base

        const int  j   = x - col + (FW_ / 2);
        const int  jc  = clamp63(j);
        const bool jok = (unsigned)j < (unsigned)FW_;
        const int  i0  = ybase - row + (FH_ / 2);
        // Wave-uniform: i0 for this wave's lanes is A or A+1. Row q live iff
        // A+8q intersects [0,63] for some lane, i.e. A+8q in [-1,63].
        const int  A   = ty0 + ybw - row + (FH_ / 2);

        if (A >=  -1 && A <= 63) {                       // q=0
            const float va = f[clamp63(i0) * FW_ + jc];
            acc0 += (jok && (unsigned)i0 < (unsigned)FH_) ? va : 0.f;
        }
        if (A >=  -9 && A <= 55) {                       // q=1
            const int ib = i0 + 8;
            const float vb = f[clamp63(ib) * FW_ + jc];
            acc1 += (jok && (unsigned)ib < (unsigned)FH_) ? vb : 0.f;
        }
        if (A >= -17 && A <= 47) {                       // q=2
            const int ic = i0 + 16;
            const float vc = f[clamp63(ic) * FW_ + jc];
            acc2 += (jok && (unsigned)ic < (unsigned)FH_) ? vc : 0.f;
        }
        if (A >= -25 && A <= 39) {                       // q=3
            const int id = i0 + 24;
            const float vd = f[clamp63(id) * FW_ + jc];
            acc3 += (jok && (unsigned)id < (unsigned)FH_) ? vd : 0.f;
        }
    };

    int k = 0;
    for (; k + 4 <= cnt; k += 4) {
        // 4 wave-uniform entries in one 16B LDS read (k%4==0 -> aligned)
        const uint4 vv = *(const uint4*)&s_list[k];
        body(vv.x); body(vv.y); body(vv.z); body(vv.w);
    }
    for (; k < cnt; ++k) body(s_list[k]);

    // ---- Epilogue: combine segments via device-scope fp32 atomics ----
    atomicAdd(&out[(ybase +  0) * W_ + x], acc0);
    atomicAdd(&out[(ybase +  8) * W_ + x], acc1);
    atomicAdd(&out[(ybase + 16) * W_ + x], acc2);
    atomicAdd(&out[(ybase + 24) * W_ + x], acc3);
}

extern "C" void kernel_launch(void* const* d_in, const int* in_sizes, int n_in,
                              void* d_out, int out_size, void* d_ws, size_t ws_size,
                              hipStream_t stream) {
    const int*   phw     = (const int*)d_in[0];
    const float* filters = (const float*)d_in[1];
    float*       out     = (float*)d_out;
    const int n = in_sizes[0] / 3;

    // Output is accumulated with atomics -> must start from zero every call
    // (harness poisons d_out with 0xAA). Async memset is graph-capture safe.
    hipMemsetAsync(out, 0, (size_t)H_ * W_ * sizeof(float), stream);

    if (n <= 0) return;

    const int segs = (n + SEG_LEN_ - 1) / SEG_LEN_;
    dim3 grid(W_ / TILE_, H_ / TILE_, segs);
    render_tile_kernel<<<grid, dim3(THREADS_), 0, stream>>>(phw, filters, out, n);
}